// Round 19
// baseline (244.958 us; speedup 1.0000x reference)
//
#include <hip/hip_runtime.h>
#include <hip/hip_bf16.h>
#include <stdint.h>

#define S_ 2048
#define H_ 16
#define KVH_ 8
#define HD_ 128

typedef short bf16x8 __attribute__((ext_vector_type(8)));
typedef float f32x4 __attribute__((ext_vector_type(4)));

__device__ __forceinline__ unsigned short f2bf(float f) {
    union { float f; uint32_t u; } v; v.f = f;
    uint32_t u = v.u;
    return (unsigned short)((u + 0x7FFFu + ((u >> 16) & 1u)) >> 16);
}
__device__ __forceinline__ float bf2f(unsigned short s) {
    union { uint32_t u; float f; } v; v.u = ((uint32_t)s) << 16;
    return v.f;
}
// async global->LDS, 16B per lane. LDS dest = wave-uniform base + lane*16 (HW).
__device__ __forceinline__ void gload16(const void* g, void* l) {
    __builtin_amdgcn_global_load_lds(
        (const __attribute__((address_space(1))) unsigned int*)(uintptr_t)g,
        (__attribute__((address_space(3))) unsigned int*)(unsigned int)(uintptr_t)l,
        16, 0, 0);
}
// 16-lane-row sum via DPP row_ror (VALU-only)
__device__ __forceinline__ float rowred_sum(float x) {
    float t;
    t = __int_as_float(__builtin_amdgcn_update_dpp(0, __float_as_int(x), 0x121, 0xF, 0xF, true)); x += t;
    t = __int_as_float(__builtin_amdgcn_update_dpp(0, __float_as_int(x), 0x122, 0xF, 0xF, true)); x += t;
    t = __int_as_float(__builtin_amdgcn_update_dpp(0, __float_as_int(x), 0x124, 0xF, 0xF, true)); x += t;
    t = __int_as_float(__builtin_amdgcn_update_dpp(0, __float_as_int(x), 0x128, 0xF, 0xF, true)); x += t;
    return x;
}

// ------------- fused prep: fp32->bf16 conv (blocks 0..2047) + 4 weight transposes -------------
__global__ __launch_bounds__(256) void k_prep(
    const float* __restrict__ hidden, unsigned short* __restrict__ Xb,
    const float* __restrict__ qk, const float* __restrict__ kk,
    const float* __restrict__ vk, const float* __restrict__ ok,
    unsigned short* __restrict__ Wqkvt, unsigned short* __restrict__ Wot) {
    const int tid = threadIdx.x;
    if (blockIdx.x < 2048) {
        int i = blockIdx.x * 256 + tid;
        const int stride = 2048 * 256;
        #pragma unroll
        for (int u = 0; u < 4; u++, i += stride) {
            float4 f = ((const float4*)hidden)[i];
            ushort4 o;
            o.x = f2bf(f.x); o.y = f2bf(f.y); o.z = f2bf(f.z); o.w = f2bf(f.w);
            ((ushort4*)Xb)[i] = o;
        }
    } else {
        __shared__ float tile[32][33];
        const int t = blockIdx.x - 2048;
        const float* src; unsigned short* dst; int N, bx, by;
        if (t < 4096)      { src = qk; dst = Wqkvt;                          N = 2048; bx = t & 63; by = t >> 6; }
        else if (t < 6144) { int u = t - 4096; src = kk; dst = Wqkvt + (size_t)2048 * 2048; N = 1024; bx = u & 31; by = u >> 5; }
        else if (t < 8192) { int u = t - 6144; src = vk; dst = Wqkvt + (size_t)3072 * 2048; N = 1024; bx = u & 31; by = u >> 5; }
        else               { int u = t - 8192; src = ok; dst = Wot;          N = 2048; bx = u & 63; by = u >> 6; }
        const int n0 = bx * 32, k0 = by * 32;
        const int tx = tid & 31, ty = tid >> 5;
        #pragma unroll
        for (int j = 0; j < 32; j += 8)
            tile[ty + j][tx] = src[(size_t)(k0 + ty + j) * N + n0 + tx];
        __syncthreads();
        #pragma unroll
        for (int j = 0; j < 32; j += 8)
            dst[(size_t)(n0 + ty + j) * 2048 + k0 + tx] = f2bf(tile[tx][ty + j]);
    }
}

// ------------- BMx256-tile bf16 GEMM (8 waves, BK=32, swizzled LDS, counted vmcnt) -----
template <int BM, int OUT_F32>
__global__ __launch_bounds__(512) void k_gemm256(const unsigned short* __restrict__ A,
                                                 const unsigned short* __restrict__ Bt,
                                                 void* __restrict__ Cv,
                                                 int M, int N, int K) {
    __shared__ __align__(16) unsigned short As[2][BM * 32];
    __shared__ __align__(16) unsigned short Bs[2][256 * 32];
    const int tid = threadIdx.x;
    const int wave = tid >> 6, lane = tid & 63;
    const int lm = lane & 15, lg = lane >> 4;
    const int wr = wave >> 2, wc = wave & 3;
    const int m0 = blockIdx.y * BM, n0 = blockIdx.x * 256;
    constexpr int MF = BM / 32;
    f32x4 acc[MF][4] = {};
    const int srow = wave * 16 + (lane >> 2);
    const int sslot = (lane & 3) ^ ((lane >> 3) & 3);
    const unsigned short* gA = A + (size_t)(m0 + srow) * K + sslot * 8;
    const unsigned short* gB = Bt + (size_t)(n0 + srow) * K + sslot * 8;
    const int swz = lg ^ ((lm >> 1) & 3);
    const int NKT = K >> 5;

    auto STAGE = [&](int kt, int buf) {
        const int c = kt * 32;
        char* lA = (char*)&As[buf][0] + wave * 1024;
        char* lB = (char*)&Bs[buf][0] + wave * 1024;
        gload16(gA + c, lA);
        if constexpr (BM == 256) gload16(gA + c + (size_t)128 * K, lA + 8192);
        gload16(gB + c, lB);
        gload16(gB + c + (size_t)128 * K, lB + 8192);
    };
    STAGE(0, 0);
    for (int kt = 0; kt < NKT; ++kt) {
        const int cur = kt & 1;
        if (kt + 1 < NKT) {
            STAGE(kt + 1, cur ^ 1);
            __builtin_amdgcn_sched_barrier(0);
            if constexpr (BM == 256) asm volatile("s_waitcnt vmcnt(4)" ::: "memory");
            else                     asm volatile("s_waitcnt vmcnt(3)" ::: "memory");
        } else {
            __builtin_amdgcn_sched_barrier(0);
            asm volatile("s_waitcnt vmcnt(0)" ::: "memory");
        }
        __builtin_amdgcn_s_barrier();
        __builtin_amdgcn_sched_barrier(0);
        bf16x8 bfr[4];
        #pragma unroll
        for (int n = 0; n < 4; n++)
            bfr[n] = *(const bf16x8*)&Bs[cur][(wc * 64 + n * 16 + lm) * 32 + swz * 8];
        __builtin_amdgcn_s_setprio(1);
        #pragma unroll
        for (int m = 0; m < MF; m++) {
            bf16x8 a = *(const bf16x8*)&As[cur][(wr * (BM / 2) + m * 16 + lm) * 32 + swz * 8];
            #pragma unroll
            for (int n = 0; n < 4; n++)
                acc[m][n] = __builtin_amdgcn_mfma_f32_16x16x32_bf16(a, bfr[n], acc[m][n], 0, 0, 0);
        }
        __builtin_amdgcn_s_setprio(0);
        __builtin_amdgcn_sched_barrier(0);
        __builtin_amdgcn_s_barrier();
        __builtin_amdgcn_sched_barrier(0);
    }
    #pragma unroll
    for (int m = 0; m < MF; m++) {
        const int row = m0 + wr * (BM / 2) + m * 16 + lg * 4;
        #pragma unroll
        for (int n = 0; n < 4; n++) {
            const int col = n0 + wc * 64 + n * 16 + lm;
            #pragma unroll
            for (int i = 0; i < 4; i++) {
                if (OUT_F32) ((float*)Cv)[(size_t)(row + i) * N + col] = acc[m][n][i];
                else ((unsigned short*)Cv)[(size_t)(row + i) * N + col] = f2bf(acc[m][n][i]);
            }
        }
    }
}

// ------------- fused: per-head RMSNorm+RoPE (blocks 0..4095) + V transpose (4096..8191) ----
// Q is pre-scaled by (1/sqrt(HD))*log2(e): attn scores land in the exp2 domain.
__global__ __launch_bounds__(256) void k_normvt(
    const unsigned short* __restrict__ Cqkv,
    const float* __restrict__ cosb, const float* __restrict__ sinb,
    const float* __restrict__ qw, const float* __restrict__ kw,
    unsigned short* __restrict__ Qb, unsigned short* __restrict__ Kb,
    unsigned short* __restrict__ Vtg) {
    const int tid = threadIdx.x;
    if (blockIdx.x < 4096) {
        const int row = blockIdx.x;  // b*S+s
        const int b = row >> 11, s = row & (S_ - 1);
        const int wave = tid >> 6, lane = tid & 63;
        const float QSCALE = 0.12753102543609668f;  // (1/sqrt(128)) * log2(e)
        const float c0 = cosb[(size_t)row * HD_ + lane];
        const float c1 = cosb[(size_t)row * HD_ + lane + 64];
        const float s0 = sinb[(size_t)row * HD_ + lane];
        const float s1 = sinb[(size_t)row * HD_ + lane + 64];
        for (int u = wave; u < 24; u += 4) {
            const int isq = (u < 16);
            const int head = isq ? u : u - 16;
            const unsigned short* x = Cqkv + (size_t)row * 4096 + (isq ? 0 : 2048) + head * HD_;
            float x0 = bf2f(x[lane]), x1 = bf2f(x[lane + 64]);
            float ss = x0 * x0 + x1 * x1;
            #pragma unroll
            for (int o = 32; o >= 1; o >>= 1) ss += __shfl_xor(ss, o, 64);
            float r = rsqrtf(ss * (1.0f / HD_) + 1e-6f);
            const float* wv = isq ? qw : kw;
            float y0 = x0 * r * wv[lane], y1 = x1 * r * wv[lane + 64];
            float o0 = y0 * c0 - y1 * s0;
            float o1 = y1 * c1 + y0 * s1;
            if (isq) { o0 *= QSCALE; o1 *= QSCALE; }
            unsigned short* dst = isq ? Qb + ((size_t)(b * H_ + head) * S_ + s) * HD_
                                      : Kb + ((size_t)(b * KVH_ + head) * S_ + s) * HD_;
            dst[lane] = f2bf(o0);
            dst[lane + 64] = f2bf(o1);
        }
    } else {
        __shared__ unsigned short tile[32][34];
        const int t = blockIdx.x - 4096;
        const int x = t & 63, y = (t >> 6) & 3, bkh = t >> 8;
        const int b = bkh >> 3, kh = bkh & 7;
        const int s0 = x * 32, d0 = y * 32;
        const int tx = tid & 31, ty = tid >> 5;
        #pragma unroll
        for (int j = 0; j < 32; j += 8)
            tile[ty + j][tx] = Cqkv[(size_t)(b * S_ + s0 + ty + j) * 4096 + 3072 + kh * HD_ + d0 + tx];
        __syncthreads();
        #pragma unroll
        for (int j = 0; j < 32; j += 8)
            Vtg[((size_t)bkh * HD_ + d0 + ty + j) * S_ + s0 + tx] = tile[tx][ty + j];
    }
}

// ------------- flash attention: QBLK=128 (4 waves x 32 rows), KVBLK=64 -------------
// R18 structure + exp2-domain softmax (Q pre-scaled; no per-score mul; exp2f direct).
// No online-max (norm-bounded scores); masked-last-tile skip; pair-balanced qi.
__global__ __launch_bounds__(256) void k_attn(
    const unsigned short* __restrict__ Qb,   // [B][H][S][HD]  (pre-scaled)
    const unsigned short* __restrict__ Kb,   // [B][KVH][S][HD]
    const unsigned short* __restrict__ Vtg,  // [B][KVH][HD][S]  (transposed)
    unsigned short* __restrict__ AO) {       // [B][S][H*HD]
    __shared__ __align__(16) unsigned short Kt[2][64 * 128];
    __shared__ __align__(16) unsigned short Vt[2][128 * 64];
    __shared__ __align__(16) unsigned short Pl[4][16][72];
    const int h = blockIdx.y, b = blockIdx.z;
    const int qi = (b == 0) ? (gridDim.x - 1 - blockIdx.x) : blockIdx.x;
    const int kh = h >> 1;
    const int tid = threadIdx.x, wave = tid >> 6, lane = tid & 63;
    const int lm = lane & 15, lg = lane >> 4;
    const int q0 = qi * 128;
    bf16x8 qf[2][4];
    #pragma unroll
    for (int rg = 0; rg < 2; rg++) {
        const unsigned short* Qp = Qb + ((size_t)(b * H_ + h) * S_ + q0 + wave * 32 + rg * 16 + lm) * HD_;
        #pragma unroll
        for (int d0 = 0; d0 < 4; d0++) qf[rg][d0] = *(const bf16x8*)(Qp + d0 * 32 + lg * 8);
    }
    f32x4 accO[2][8] = {};
    float lrow[2][4];
    #pragma unroll
    for (int rg = 0; rg < 2; rg++)
        #pragma unroll
        for (int i = 0; i < 4; i++) lrow[rg][i] = 0.f;
    const unsigned short* Kg = Kb + (size_t)(b * KVH_ + kh) * S_ * HD_;
    const unsigned short* Vg = Vtg + (size_t)(b * KVH_ + kh) * HD_ * S_;
    const int kr = wave * 4 + (lane >> 4);
    const int kc = ((lane & 15) ^ (kr & 7)) * 8;
    const int vr = wave * 8 + (lane >> 3);
    const int vc = ((lane & 7) ^ (vr & 7)) * 8;
    const int NT = 2 * qi + 2;

    auto STAGE = [&](int t, int buf) {
        const int k0 = t * 64;
        char* lK = (char*)&Kt[buf][0] + wave * 1024;
        char* lV = (char*)&Vt[buf][0] + wave * 1024;
        #pragma unroll
        for (int j = 0; j < 4; ++j) {
            gload16(Kg + (size_t)(k0 + kr + j * 16) * HD_ + kc, lK + j * 4096);
            gload16(Vg + (size_t)(vr + j * 32) * S_ + k0 + vc, lV + j * 4096);
        }
    };
    STAGE(0, 0);
    for (int t = 0; t < NT; ++t) {
        const int cur = t & 1;
        const int k0 = t * 64;
        if (t + 1 < NT) {
            STAGE(t + 1, cur ^ 1);
            __builtin_amdgcn_sched_barrier(0);
            asm volatile("s_waitcnt vmcnt(8)" ::: "memory");
        } else {
            __builtin_amdgcn_sched_barrier(0);
            asm volatile("s_waitcnt vmcnt(0)" ::: "memory");
        }
        __builtin_amdgcn_s_barrier();
        __builtin_amdgcn_sched_barrier(0);
        // fully-masked tile for this wave? (last tile covers kv >= q0+64; waves 0-1 rows < q0+64)
        if (!(t == 2 * qi + 1 && wave < 2)) {
            f32x4 sc[2][4] = {};
            __builtin_amdgcn_s_setprio(1);
            #pragma unroll
            for (int nk = 0; nk < 4; nk++)
                #pragma unroll
                for (int d0 = 0; d0 < 4; d0++) {
                    bf16x8 kf = *(const bf16x8*)&Kt[cur][(nk * 16 + lm) * 128 +
                                                        ((d0 * 32 + lg * 8) ^ ((lm & 7) << 3))];
                    sc[0][nk] = __builtin_amdgcn_mfma_f32_16x16x32_bf16(qf[0][d0], kf, sc[0][nk], 0, 0, 0);
                    sc[1][nk] = __builtin_amdgcn_mfma_f32_16x16x32_bf16(qf[1][d0], kf, sc[1][nk], 0, 0, 0);
                }
            __builtin_amdgcn_s_setprio(0);
            const bool diag = (t >= 2 * qi);
            #pragma unroll
            for (int rg = 0; rg < 2; rg++) {
                const int qrow0 = q0 + wave * 32 + rg * 16;
                float rs[4] = { 0.f, 0.f, 0.f, 0.f };
                #pragma unroll
                for (int nk = 0; nk < 4; nk++)
                    #pragma unroll
                    for (int i = 0; i < 4; i++) {
                        float v = sc[rg][nk][i];  // exp2-domain (Q pre-scaled)
                        if (diag && (k0 + nk * 16 + lm) > (qrow0 + lg * 4 + i)) v = -1e30f;
                        float p = exp2f(v);
                        rs[i] += p;
                        Pl[wave][lg * 4 + i][nk * 16 + lm] = f2bf(p);
                    }
                #pragma unroll
                for (int i = 0; i < 4; i++) rs[i] = rowred_sum(rs[i]);
                #pragma unroll
                for (int i = 0; i < 4; i++) lrow[rg][i] += rs[i];
                __builtin_amdgcn_s_setprio(1);
                #pragma unroll
                for (int kk = 0; kk < 2; kk++) {
                    bf16x8 pa = *(const bf16x8*)&Pl[wave][lm][kk * 32 + lg * 8];
                    #pragma unroll
                    for (int df = 0; df < 8; df++) {
                        bf16x8 vf = *(const bf16x8*)&Vt[cur][(df * 16 + lm) * 64 +
                                                             ((kk * 32 + lg * 8) ^ ((lm & 7) << 3))];
                        accO[rg][df] = __builtin_amdgcn_mfma_f32_16x16x32_bf16(pa, vf, accO[rg][df], 0, 0, 0);
                    }
                }
                __builtin_amdgcn_s_setprio(0);
            }
        }
        __builtin_amdgcn_sched_barrier(0);
        __builtin_amdgcn_s_barrier();
        __builtin_amdgcn_sched_barrier(0);
    }
    #pragma unroll
    for (int rg = 0; rg < 2; rg++) {
        unsigned short* Op = AO + ((size_t)b * S_ + q0 + wave * 32 + rg * 16) * (H_ * HD_) + h * HD_;
        #pragma unroll
        for (int df = 0; df < 8; df++)
            #pragma unroll
            for (int i = 0; i < 4; i++) {
                float v = accO[rg][df][i] / lrow[rg][i];
                Op[(size_t)(lg * 4 + i) * (H_ * HD_) + df * 16 + lm] = f2bf(v);
            }
    }
}

extern "C" void kernel_launch(void* const* d_in, const int* in_sizes, int n_in,
                              void* d_out, int out_size, void* d_ws, size_t ws_size,
                              hipStream_t stream) {
    const float* hidden = (const float*)d_in[0];
    const float* cosb = (const float*)d_in[1];
    const float* sinb = (const float*)d_in[2];
    // d_in[3] = attention_mask: pure causal, applied analytically
    const float* qk = (const float*)d_in[4];
    const float* kk = (const float*)d_in[5];
    const float* vk = (const float*)d_in[6];
    const float* ok = (const float*)d_in[7];
    const float* qw = (const float*)d_in[8];
    const float* kw = (const float*)d_in[9];
    char* ws = (char*)d_ws;
    // region reuse: all regions fully rewritten every launch (graph-replay safe)
    unsigned short* Xb    = (unsigned short*)ws;                      // 0-16 MiB (later Qb)
    unsigned short* Wqkvt = (unsigned short*)(ws + (16u << 20));      // 16-32 MiB (later Kb/Vtg)
    unsigned short* Wot   = (unsigned short*)(ws + (32u << 20));      // 32-40 MiB
    unsigned short* Cqkv  = (unsigned short*)(ws + (40u << 20));      // 40-72 MiB (later AO)
    unsigned short* Qb  = Xb;                                         // 0-16
    unsigned short* Kb  = Wqkvt;                                      // 16-24
    unsigned short* Vtg = (unsigned short*)(ws + (24u << 20));        // 24-32
    unsigned short* AO  = Cqkv;                                       // 40-56

    k_prep<<<14336, 256, 0, stream>>>(hidden, Xb, qk, kk, vk, ok, Wqkvt, Wot);
    k_gemm256<256, 0><<<dim3(16, 16), 512, 0, stream>>>(Xb, Wqkvt, Cqkv, 4096, 4096, 2048);
    k_normvt<<<8192, 256, 0, stream>>>(Cqkv, cosb, sinb, qw, kw, Qb, Kb, Vtg);
    k_attn<<<dim3(16, H_, 2), 256, 0, stream>>>(Qb, Kb, Vtg, AO);
    k_gemm256<128, 1><<<dim3(8, 32), 512, 0, stream>>>(AO, Wot, d_out, 4096, 2048, 2048);
}

// Round 20
// 232.044 us; speedup vs baseline: 1.0557x; 1.0557x over previous
//
#include <hip/hip_runtime.h>
#include <hip/hip_bf16.h>
#include <stdint.h>

#define S_ 2048
#define H_ 16
#define KVH_ 8
#define HD_ 128

typedef short bf16x8 __attribute__((ext_vector_type(8)));
typedef float f32x4 __attribute__((ext_vector_type(4)));

__device__ __forceinline__ unsigned short f2bf(float f) {
    union { float f; uint32_t u; } v; v.f = f;
    uint32_t u = v.u;
    return (unsigned short)((u + 0x7FFFu + ((u >> 16) & 1u)) >> 16);
}
__device__ __forceinline__ float bf2f(unsigned short s) {
    union { uint32_t u; float f; } v; v.u = ((uint32_t)s) << 16;
    return v.f;
}
// native v_exp_f32: D = 2^S0 (single instruction)
__device__ __forceinline__ float fast_exp2(float x) { return __builtin_amdgcn_exp2f(x); }
// async global->LDS, 16B per lane. LDS dest = wave-uniform base + lane*16 (HW).
__device__ __forceinline__ void gload16(const void* g, void* l) {
    __builtin_amdgcn_global_load_lds(
        (const __attribute__((address_space(1))) unsigned int*)(uintptr_t)g,
        (__attribute__((address_space(3))) unsigned int*)(unsigned int)(uintptr_t)l,
        16, 0, 0);
}
// 16-lane-row sum via DPP row_ror (VALU-only)
__device__ __forceinline__ float rowred_sum(float x) {
    float t;
    t = __int_as_float(__builtin_amdgcn_update_dpp(0, __float_as_int(x), 0x121, 0xF, 0xF, true)); x += t;
    t = __int_as_float(__builtin_amdgcn_update_dpp(0, __float_as_int(x), 0x122, 0xF, 0xF, true)); x += t;
    t = __int_as_float(__builtin_amdgcn_update_dpp(0, __float_as_int(x), 0x124, 0xF, 0xF, true)); x += t;
    t = __int_as_float(__builtin_amdgcn_update_dpp(0, __float_as_int(x), 0x128, 0xF, 0xF, true)); x += t;
    return x;
}

// ------------- fused prep: fp32->bf16 conv (blocks 0..2047) + 4 weight transposes -------------
__global__ __launch_bounds__(256) void k_prep(
    const float* __restrict__ hidden, unsigned short* __restrict__ Xb,
    const float* __restrict__ qk, const float* __restrict__ kk,
    const float* __restrict__ vk, const float* __restrict__ ok,
    unsigned short* __restrict__ Wqkvt, unsigned short* __restrict__ Wot) {
    const int tid = threadIdx.x;
    if (blockIdx.x < 2048) {
        int i = blockIdx.x * 256 + tid;
        const int stride = 2048 * 256;
        #pragma unroll
        for (int u = 0; u < 4; u++, i += stride) {
            float4 f = ((const float4*)hidden)[i];
            ushort4 o;
            o.x = f2bf(f.x); o.y = f2bf(f.y); o.z = f2bf(f.z); o.w = f2bf(f.w);
            ((ushort4*)Xb)[i] = o;
        }
    } else {
        __shared__ float tile[32][33];
        const int t = blockIdx.x - 2048;
        const float* src; unsigned short* dst; int N, bx, by;
        if (t < 4096)      { src = qk; dst = Wqkvt;                          N = 2048; bx = t & 63; by = t >> 6; }
        else if (t < 6144) { int u = t - 4096; src = kk; dst = Wqkvt + (size_t)2048 * 2048; N = 1024; bx = u & 31; by = u >> 5; }
        else if (t < 8192) { int u = t - 6144; src = vk; dst = Wqkvt + (size_t)3072 * 2048; N = 1024; bx = u & 31; by = u >> 5; }
        else               { int u = t - 8192; src = ok; dst = Wot;          N = 2048; bx = u & 63; by = u >> 6; }
        const int n0 = bx * 32, k0 = by * 32;
        const int tx = tid & 31, ty = tid >> 5;
        #pragma unroll
        for (int j = 0; j < 32; j += 8)
            tile[ty + j][tx] = src[(size_t)(k0 + ty + j) * N + n0 + tx];
        __syncthreads();
        #pragma unroll
        for (int j = 0; j < 32; j += 8)
            dst[(size_t)(n0 + ty + j) * 2048 + k0 + tx] = f2bf(tile[tx][ty + j]);
    }
}

// ------------- BMx256-tile bf16 GEMM (8 waves, BK=32, swizzled LDS, counted vmcnt) -----
template <int BM, int OUT_F32>
__global__ __launch_bounds__(512) void k_gemm256(const unsigned short* __restrict__ A,
                                                 const unsigned short* __restrict__ Bt,
                                                 void* __restrict__ Cv,
                                                 int M, int N, int K) {
    __shared__ __align__(16) unsigned short As[2][BM * 32];
    __shared__ __align__(16) unsigned short Bs[2][256 * 32];
    const int tid = threadIdx.x;
    const int wave = tid >> 6, lane = tid & 63;
    const int lm = lane & 15, lg = lane >> 4;
    const int wr = wave >> 2, wc = wave & 3;
    const int m0 = blockIdx.y * BM, n0 = blockIdx.x * 256;
    constexpr int MF = BM / 32;
    f32x4 acc[MF][4] = {};
    const int srow = wave * 16 + (lane >> 2);
    const int sslot = (lane & 3) ^ ((lane >> 3) & 3);
    const unsigned short* gA = A + (size_t)(m0 + srow) * K + sslot * 8;
    const unsigned short* gB = Bt + (size_t)(n0 + srow) * K + sslot * 8;
    const int swz = lg ^ ((lm >> 1) & 3);
    const int NKT = K >> 5;

    auto STAGE = [&](int kt, int buf) {
        const int c = kt * 32;
        char* lA = (char*)&As[buf][0] + wave * 1024;
        char* lB = (char*)&Bs[buf][0] + wave * 1024;
        gload16(gA + c, lA);
        if constexpr (BM == 256) gload16(gA + c + (size_t)128 * K, lA + 8192);
        gload16(gB + c, lB);
        gload16(gB + c + (size_t)128 * K, lB + 8192);
    };
    STAGE(0, 0);
    for (int kt = 0; kt < NKT; ++kt) {
        const int cur = kt & 1;
        if (kt + 1 < NKT) {
            STAGE(kt + 1, cur ^ 1);
            __builtin_amdgcn_sched_barrier(0);
            if constexpr (BM == 256) asm volatile("s_waitcnt vmcnt(4)" ::: "memory");
            else                     asm volatile("s_waitcnt vmcnt(3)" ::: "memory");
        } else {
            __builtin_amdgcn_sched_barrier(0);
            asm volatile("s_waitcnt vmcnt(0)" ::: "memory");
        }
        __builtin_amdgcn_s_barrier();
        __builtin_amdgcn_sched_barrier(0);
        bf16x8 bfr[4];
        #pragma unroll
        for (int n = 0; n < 4; n++)
            bfr[n] = *(const bf16x8*)&Bs[cur][(wc * 64 + n * 16 + lm) * 32 + swz * 8];
        __builtin_amdgcn_s_setprio(1);
        #pragma unroll
        for (int m = 0; m < MF; m++) {
            bf16x8 a = *(const bf16x8*)&As[cur][(wr * (BM / 2) + m * 16 + lm) * 32 + swz * 8];
            #pragma unroll
            for (int n = 0; n < 4; n++)
                acc[m][n] = __builtin_amdgcn_mfma_f32_16x16x32_bf16(a, bfr[n], acc[m][n], 0, 0, 0);
        }
        __builtin_amdgcn_s_setprio(0);
        __builtin_amdgcn_sched_barrier(0);
        __builtin_amdgcn_s_barrier();
        __builtin_amdgcn_sched_barrier(0);
    }
    #pragma unroll
    for (int m = 0; m < MF; m++) {
        const int row = m0 + wr * (BM / 2) + m * 16 + lg * 4;
        #pragma unroll
        for (int n = 0; n < 4; n++) {
            const int col = n0 + wc * 64 + n * 16 + lm;
            #pragma unroll
            for (int i = 0; i < 4; i++) {
                if (OUT_F32) ((float*)Cv)[(size_t)(row + i) * N + col] = acc[m][n][i];
                else ((unsigned short*)Cv)[(size_t)(row + i) * N + col] = f2bf(acc[m][n][i]);
            }
        }
    }
}

// ------------- fused: per-head RMSNorm+RoPE (blocks 0..4095) + V transpose (4096..8191) ----
// Q is pre-scaled by (1/sqrt(HD))*log2(e): attn scores land in the exp2 domain.
__global__ __launch_bounds__(256) void k_normvt(
    const unsigned short* __restrict__ Cqkv,
    const float* __restrict__ cosb, const float* __restrict__ sinb,
    const float* __restrict__ qw, const float* __restrict__ kw,
    unsigned short* __restrict__ Qb, unsigned short* __restrict__ Kb,
    unsigned short* __restrict__ Vtg) {
    const int tid = threadIdx.x;
    if (blockIdx.x < 4096) {
        const int row = blockIdx.x;  // b*S+s
        const int b = row >> 11, s = row & (S_ - 1);
        const int wave = tid >> 6, lane = tid & 63;
        const float QSCALE = 0.12753102543609668f;  // (1/sqrt(128)) * log2(e)
        const float c0 = cosb[(size_t)row * HD_ + lane];
        const float c1 = cosb[(size_t)row * HD_ + lane + 64];
        const float s0 = sinb[(size_t)row * HD_ + lane];
        const float s1 = sinb[(size_t)row * HD_ + lane + 64];
        for (int u = wave; u < 24; u += 4) {
            const int isq = (u < 16);
            const int head = isq ? u : u - 16;
            const unsigned short* x = Cqkv + (size_t)row * 4096 + (isq ? 0 : 2048) + head * HD_;
            float x0 = bf2f(x[lane]), x1 = bf2f(x[lane + 64]);
            float ss = x0 * x0 + x1 * x1;
            #pragma unroll
            for (int o = 32; o >= 1; o >>= 1) ss += __shfl_xor(ss, o, 64);
            float r = rsqrtf(ss * (1.0f / HD_) + 1e-6f);
            const float* wv = isq ? qw : kw;
            float y0 = x0 * r * wv[lane], y1 = x1 * r * wv[lane + 64];
            float o0 = y0 * c0 - y1 * s0;
            float o1 = y1 * c1 + y0 * s1;
            if (isq) { o0 *= QSCALE; o1 *= QSCALE; }
            unsigned short* dst = isq ? Qb + ((size_t)(b * H_ + head) * S_ + s) * HD_
                                      : Kb + ((size_t)(b * KVH_ + head) * S_ + s) * HD_;
            dst[lane] = f2bf(o0);
            dst[lane + 64] = f2bf(o1);
        }
    } else {
        __shared__ unsigned short tile[32][34];
        const int t = blockIdx.x - 4096;
        const int x = t & 63, y = (t >> 6) & 3, bkh = t >> 8;
        const int b = bkh >> 3, kh = bkh & 7;
        const int s0 = x * 32, d0 = y * 32;
        const int tx = tid & 31, ty = tid >> 5;
        #pragma unroll
        for (int j = 0; j < 32; j += 8)
            tile[ty + j][tx] = Cqkv[(size_t)(b * S_ + s0 + ty + j) * 4096 + 3072 + kh * HD_ + d0 + tx];
        __syncthreads();
        #pragma unroll
        for (int j = 0; j < 32; j += 8)
            Vtg[((size_t)bkh * HD_ + d0 + ty + j) * S_ + s0 + tx] = tile[tx][ty + j];
    }
}

// ------------- flash attention: QBLK=128 (4 waves x 32 rows), KVBLK=64 -------------
// R18 structure + exp2-domain softmax via native v_exp_f32 (__builtin_amdgcn_exp2f).
// No online-max (norm-bounded scores); masked-last-tile skip; pair-balanced qi.
__global__ __launch_bounds__(256) void k_attn(
    const unsigned short* __restrict__ Qb,   // [B][H][S][HD]  (pre-scaled)
    const unsigned short* __restrict__ Kb,   // [B][KVH][S][HD]
    const unsigned short* __restrict__ Vtg,  // [B][KVH][HD][S]  (transposed)
    unsigned short* __restrict__ AO) {       // [B][S][H*HD]
    __shared__ __align__(16) unsigned short Kt[2][64 * 128];
    __shared__ __align__(16) unsigned short Vt[2][128 * 64];
    __shared__ __align__(16) unsigned short Pl[4][16][72];
    const int h = blockIdx.y, b = blockIdx.z;
    const int qi = (b == 0) ? (gridDim.x - 1 - blockIdx.x) : blockIdx.x;
    const int kh = h >> 1;
    const int tid = threadIdx.x, wave = tid >> 6, lane = tid & 63;
    const int lm = lane & 15, lg = lane >> 4;
    const int q0 = qi * 128;
    bf16x8 qf[2][4];
    #pragma unroll
    for (int rg = 0; rg < 2; rg++) {
        const unsigned short* Qp = Qb + ((size_t)(b * H_ + h) * S_ + q0 + wave * 32 + rg * 16 + lm) * HD_;
        #pragma unroll
        for (int d0 = 0; d0 < 4; d0++) qf[rg][d0] = *(const bf16x8*)(Qp + d0 * 32 + lg * 8);
    }
    f32x4 accO[2][8] = {};
    float lrow[2][4];
    #pragma unroll
    for (int rg = 0; rg < 2; rg++)
        #pragma unroll
        for (int i = 0; i < 4; i++) lrow[rg][i] = 0.f;
    const unsigned short* Kg = Kb + (size_t)(b * KVH_ + kh) * S_ * HD_;
    const unsigned short* Vg = Vtg + (size_t)(b * KVH_ + kh) * HD_ * S_;
    const int kr = wave * 4 + (lane >> 4);
    const int kc = ((lane & 15) ^ (kr & 7)) * 8;
    const int vr = wave * 8 + (lane >> 3);
    const int vc = ((lane & 7) ^ (vr & 7)) * 8;
    const int NT = 2 * qi + 2;

    auto STAGE = [&](int t, int buf) {
        const int k0 = t * 64;
        char* lK = (char*)&Kt[buf][0] + wave * 1024;
        char* lV = (char*)&Vt[buf][0] + wave * 1024;
        #pragma unroll
        for (int j = 0; j < 4; ++j) {
            gload16(Kg + (size_t)(k0 + kr + j * 16) * HD_ + kc, lK + j * 4096);
            gload16(Vg + (size_t)(vr + j * 32) * S_ + k0 + vc, lV + j * 4096);
        }
    };
    STAGE(0, 0);
    for (int t = 0; t < NT; ++t) {
        const int cur = t & 1;
        const int k0 = t * 64;
        if (t + 1 < NT) {
            STAGE(t + 1, cur ^ 1);
            __builtin_amdgcn_sched_barrier(0);
            asm volatile("s_waitcnt vmcnt(8)" ::: "memory");
        } else {
            __builtin_amdgcn_sched_barrier(0);
            asm volatile("s_waitcnt vmcnt(0)" ::: "memory");
        }
        __builtin_amdgcn_s_barrier();
        __builtin_amdgcn_sched_barrier(0);
        // fully-masked tile for this wave? (last tile covers kv >= q0+64; waves 0-1 rows < q0+64)
        if (!(t == 2 * qi + 1 && wave < 2)) {
            f32x4 sc[2][4] = {};
            __builtin_amdgcn_s_setprio(1);
            #pragma unroll
            for (int nk = 0; nk < 4; nk++)
                #pragma unroll
                for (int d0 = 0; d0 < 4; d0++) {
                    bf16x8 kf = *(const bf16x8*)&Kt[cur][(nk * 16 + lm) * 128 +
                                                        ((d0 * 32 + lg * 8) ^ ((lm & 7) << 3))];
                    sc[0][nk] = __builtin_amdgcn_mfma_f32_16x16x32_bf16(qf[0][d0], kf, sc[0][nk], 0, 0, 0);
                    sc[1][nk] = __builtin_amdgcn_mfma_f32_16x16x32_bf16(qf[1][d0], kf, sc[1][nk], 0, 0, 0);
                }
            __builtin_amdgcn_s_setprio(0);
            const bool diag = (t >= 2 * qi);
            #pragma unroll
            for (int rg = 0; rg < 2; rg++) {
                const int qrow0 = q0 + wave * 32 + rg * 16;
                float rs[4] = { 0.f, 0.f, 0.f, 0.f };
                #pragma unroll
                for (int nk = 0; nk < 4; nk++)
                    #pragma unroll
                    for (int i = 0; i < 4; i++) {
                        float v = sc[rg][nk][i];  // exp2-domain (Q pre-scaled)
                        if (diag && (k0 + nk * 16 + lm) > (qrow0 + lg * 4 + i)) v = -1e30f;
                        float p = fast_exp2(v);
                        rs[i] += p;
                        Pl[wave][lg * 4 + i][nk * 16 + lm] = f2bf(p);
                    }
                #pragma unroll
                for (int i = 0; i < 4; i++) rs[i] = rowred_sum(rs[i]);
                #pragma unroll
                for (int i = 0; i < 4; i++) lrow[rg][i] += rs[i];
                __builtin_amdgcn_s_setprio(1);
                #pragma unroll
                for (int kk = 0; kk < 2; kk++) {
                    bf16x8 pa = *(const bf16x8*)&Pl[wave][lm][kk * 32 + lg * 8];
                    #pragma unroll
                    for (int df = 0; df < 8; df++) {
                        bf16x8 vf = *(const bf16x8*)&Vt[cur][(df * 16 + lm) * 64 +
                                                             ((kk * 32 + lg * 8) ^ ((lm & 7) << 3))];
                        accO[rg][df] = __builtin_amdgcn_mfma_f32_16x16x32_bf16(pa, vf, accO[rg][df], 0, 0, 0);
                    }
                }
                __builtin_amdgcn_s_setprio(0);
            }
        }
        __builtin_amdgcn_sched_barrier(0);
        __builtin_amdgcn_s_barrier();
        __builtin_amdgcn_sched_barrier(0);
    }
    #pragma unroll
    for (int rg = 0; rg < 2; rg++) {
        unsigned short* Op = AO + ((size_t)b * S_ + q0 + wave * 32 + rg * 16) * (H_ * HD_) + h * HD_;
        #pragma unroll
        for (int df = 0; df < 8; df++)
            #pragma unroll
            for (int i = 0; i < 4; i++) {
                float v = accO[rg][df][i] / lrow[rg][i];
                Op[(size_t)(lg * 4 + i) * (H_ * HD_) + df * 16 + lm] = f2bf(v);
            }
    }
}

extern "C" void kernel_launch(void* const* d_in, const int* in_sizes, int n_in,
                              void* d_out, int out_size, void* d_ws, size_t ws_size,
                              hipStream_t stream) {
    const float* hidden = (const float*)d_in[0];
    const float* cosb = (const float*)d_in[1];
    const float* sinb = (const float*)d_in[2];
    // d_in[3] = attention_mask: pure causal, applied analytically
    const float* qk = (const float*)d_in[4];
    const float* kk = (const float*)d_in[5];
    const float* vk = (const float*)d_in[6];
    const float* ok = (const float*)d_in[7];
    const float* qw = (const float*)d_in[8];
    const float* kw = (const float*)d_in[9];
    char* ws = (char*)d_ws;
    // region reuse: all regions fully rewritten every launch (graph-replay safe)
    unsigned short* Xb    = (unsigned short*)ws;                      // 0-16 MiB (later Qb)
    unsigned short* Wqkvt = (unsigned short*)(ws + (16u << 20));      // 16-32 MiB (later Kb/Vtg)
    unsigned short* Wot   = (unsigned short*)(ws + (32u << 20));      // 32-40 MiB
    unsigned short* Cqkv  = (unsigned short*)(ws + (40u << 20));      // 40-72 MiB (later AO)
    unsigned short* Qb  = Xb;                                         // 0-16
    unsigned short* Kb  = Wqkvt;                                      // 16-24
    unsigned short* Vtg = (unsigned short*)(ws + (24u << 20));        // 24-32
    unsigned short* AO  = Cqkv;                                       // 40-56

    k_prep<<<14336, 256, 0, stream>>>(hidden, Xb, qk, kk, vk, ok, Wqkvt, Wot);
    k_gemm256<256, 0><<<dim3(16, 16), 512, 0, stream>>>(Xb, Wqkvt, Cqkv, 4096, 4096, 2048);
    k_normvt<<<8192, 256, 0, stream>>>(Cqkv, cosb, sinb, qw, kw, Qb, Kb, Vtg);
    k_attn<<<dim3(16, H_, 2), 256, 0, stream>>>(Qb, Kb, Vtg, AO);
    k_gemm256<128, 1><<<dim3(8, 32), 512, 0, stream>>>(AO, Wot, d_out, 4096, 2048, 2048);
}